// Round 6
// baseline (238.950 us; speedup 1.0000x reference)
//
#include <hip/hip_runtime.h>

// GraphNorm: per-graph (segmented) normalization over sorted batch ids.
// N=500000 rows, C=128 channels, B=512 graphs (reference constants).
//
// Single fused kernel, ONE 1024-thread block per graph (2 blocks/CU):
//   - inline binary search for segment bounds [s,e) (wave-uniform, cached)
//   - phase 1: nt-load segment rows ONCE, accumulate sum/sumsq AND park the
//     values in a fully-unrolled register array (~40 float4/thread = 160 VGPR;
//     256 VGPR/thread available at 2 blocks/CU)
//   - LDS tree-reduce (fixed order, deterministic) -> per-channel coeffs:
//       mean = sum/cnt; ex2 = sumsq/cnt
//       var  = ex2 - mean^2 * ms * (2 - ms)   // == E[(x-mean*ms)^2]
//       a = w * rsqrt(var+eps); d = bias - a * mean * ms
//   - phase 2: out = fma(a, xr, d) straight from registers, nt stores.
//     Rows beyond R_MAX*32 (segment >1280 rows; +9.7 sigma, ~never) are
//     re-loaded from cache for correctness.
// No cross-block communication (R3 failed on XCD L2 non-coherence).

#define C_CH 128
#define B_GR 512
#define EPSV 1e-5f
#define R_MAX 40   // max rows per thread held in registers (covers cnt <= 1280)

typedef float f32x4 __attribute__((ext_vector_type(4)));

__device__ __forceinline__ int lower_bound(const int* __restrict__ batch,
                                           int N, int key) {
    int lo = 0, hi = N;
    while (lo < hi) {
        int mid = (lo + hi) >> 1;
        if (batch[mid] < key) lo = mid + 1; else hi = mid;
    }
    return lo;
}

__global__ __launch_bounds__(1024, 8) void gn_fused(
    const float* __restrict__ x, const int* __restrict__ batch, int N,
    const float* __restrict__ w, const float* __restrict__ bias,
    const float* __restrict__ ms, float* __restrict__ out) {
    const int b   = blockIdx.x;
    const int tid = threadIdx.x;
    const int col = tid & 31;   // float4 column: channels 4*col .. 4*col+3
    const int rg  = tid >> 5;   // row group 0..31

    // segment bounds (uniform across block; batch is L2/IC-resident)
    const int s = lower_bound(batch, N, b);
    const int e = lower_bound(batch, N, b + 1);

    const f32x4* __restrict__ x4 = (const f32x4*)x;
    f32x4* __restrict__ o4 = (f32x4*)out;

    // ---- phase 1: load once, park in registers, accumulate ----
    f32x4 xr[R_MAX];
    f32x4 sum = {0.f, 0.f, 0.f, 0.f};
    f32x4 sq  = {0.f, 0.f, 0.f, 0.f};
    #pragma unroll
    for (int k = 0; k < R_MAX; ++k) {
        const int r = s + rg + 32 * k;
        if (r < e) {
            f32x4 v = __builtin_nontemporal_load(&x4[(size_t)r * (C_CH / 4) + col]);
            xr[k] = v;
            sum += v;
            sq  += v * v;
        }
    }
    // overflow rows (cnt > 32*R_MAX): still counted in sums
    for (int r = s + rg + 32 * R_MAX; r < e; r += 32) {
        f32x4 v = x4[(size_t)r * (C_CH / 4) + col];
        sum += v;
        sq  += v * v;
    }

    __shared__ f32x4 s_sum[32][32];   // [rg][col] 16KB
    __shared__ f32x4 s_sq[32][32];    // 16KB
    __shared__ float s_a[C_CH];
    __shared__ float s_d[C_CH];

    s_sum[rg][col] = sum;
    s_sq[rg][col]  = sq;

    // tree-reduce over rg (fixed order -> deterministic)
    #pragma unroll
    for (int st = 16; st >= 1; st >>= 1) {
        __syncthreads();
        if (rg < st) {
            s_sum[rg][col] += s_sum[rg + st][col];
            s_sq[rg][col]  += s_sq[rg + st][col];
        }
    }
    __syncthreads();

    // coeffs: one thread per channel
    if (tid < C_CH) {
        const int c  = tid;
        const int cc = c >> 2;
        const int j  = c & 3;
        const float fsum = s_sum[0][cc][j];
        const float fsq  = s_sq[0][cc][j];
        const int   cnt  = e - s;
        const float inv  = 1.0f / (float)max(cnt, 1);
        const float m    = fsum * inv;
        const float ex2  = fsq * inv;
        const float msc  = ms[c];
        const float var  = ex2 - m * m * msc * (2.0f - msc);
        const float rstd = rsqrtf(var + EPSV);
        const float a    = w[c] * rstd;
        s_a[c] = a;
        s_d[c] = bias[c] - a * m * msc;
    }
    __syncthreads();

    // ---- phase 2: write straight from registers ----
    const f32x4 a = ((const f32x4*)s_a)[col];
    const f32x4 d = ((const f32x4*)s_d)[col];
    #pragma unroll
    for (int k = 0; k < R_MAX; ++k) {
        const int r = s + rg + 32 * k;
        if (r < e) {
            f32x4 v = xr[k];
            f32x4 o;
            o.x = fmaf(a.x, v.x, d.x);
            o.y = fmaf(a.y, v.y, d.y);
            o.z = fmaf(a.z, v.z, d.z);
            o.w = fmaf(a.w, v.w, d.w);
            __builtin_nontemporal_store(o, &o4[(size_t)r * (C_CH / 4) + col]);
        }
    }
    // overflow rows: re-load (cache-hit) and write
    for (int r = s + rg + 32 * R_MAX; r < e; r += 32) {
        const size_t g = (size_t)r * (C_CH / 4) + col;
        f32x4 v = x4[g];
        f32x4 o;
        o.x = fmaf(a.x, v.x, d.x);
        o.y = fmaf(a.y, v.y, d.y);
        o.z = fmaf(a.z, v.z, d.z);
        o.w = fmaf(a.w, v.w, d.w);
        __builtin_nontemporal_store(o, &o4[g]);
    }
}

extern "C" void kernel_launch(void* const* d_in, const int* in_sizes, int n_in,
                              void* d_out, int out_size, void* d_ws, size_t ws_size,
                              hipStream_t stream) {
    const float* x     = (const float*)d_in[0];
    const int*   batch = (const int*)d_in[1];
    const float* w     = (const float*)d_in[2];
    const float* bias  = (const float*)d_in[3];
    const float* ms    = (const float*)d_in[4];
    const int B = B_GR;                 // reference constant (device scalar d_in[5])
    const int N = in_sizes[1];          // rows
    float* out = (float*)d_out;

    gn_fused<<<B, 1024, 0, stream>>>(x, batch, N, w, bias, ms, out);
}

// Round 7
// 121.474 us; speedup vs baseline: 1.9671x; 1.9671x over previous
//
#include <hip/hip_runtime.h>

// GraphNorm: per-graph (segmented) normalization over sorted batch ids.
// N=500000 rows, C=128 channels, B=512 graphs (reference constants).
//
// Kernel 1 (gn_bounds): starts[b] = lower_bound(batch, b), b in [0,B].
// Kernel 2 (gn_fused2): 256 blocks x 1024 threads; block i owns graphs
//   gA = i and gB = i + 256, software-pipelined:
//     phase 1A: read A rows (IC-allocating loads), sum/sumsq
//     reduce A -> coeffs (LDS tree, fixed order -> deterministic)
//     interleave: { re-read A row (IC hit, nt load) -> fma -> nt store }
//                 || { read B row (HBM), accumulate }   <- overlaps HBM write
//                                                          of A with read of B
//     reduce B -> coeffs
//     phase 2B: re-read B (IC hit) -> fma -> nt store
//   coeffs: mean = sum/cnt; ex2 = sumsq/cnt
//           var  = ex2 - mean^2 * ms * (2 - ms)   // == E[(x-mean*ms)^2]
//           a = w * rsqrt(var+eps); d = bias - a * mean * ms
// R4 proved (FETCH==250MB) that re-reads hit the 256MB Infinity Cache when
// out uses nt stores. R5 proved register parking can't fit (1024-thread
// block caps at 128 VGPR/thread). No cross-block communication (R3: XCD L2
// non-coherence).

#define C_CH 128
#define B_GR 512
#define NBLK 256
#define EPSV 1e-5f

typedef float f32x4 __attribute__((ext_vector_type(4)));

__global__ void gn_bounds(const int* __restrict__ batch, int N, int B,
                          int* __restrict__ starts) {
    int b = blockIdx.x * blockDim.x + threadIdx.x;
    if (b > B) return;
    int lo = 0, hi = N;
    while (lo < hi) {
        int mid = (lo + hi) >> 1;
        if (batch[mid] < b) lo = mid + 1; else hi = mid;
    }
    starts[b] = lo;  // for b==B all values < B, so starts[B]==N
}

__device__ __forceinline__ f32x4 ffma4(f32x4 a, f32x4 v, f32x4 d) {
    f32x4 o;
    o.x = fmaf(a.x, v.x, d.x);
    o.y = fmaf(a.y, v.y, d.y);
    o.z = fmaf(a.z, v.z, d.z);
    o.w = fmaf(a.w, v.w, d.w);
    return o;
}

__global__ __launch_bounds__(1024) void gn_fused2(
    const float* __restrict__ x, const int* __restrict__ starts,
    const float* __restrict__ w, const float* __restrict__ bias,
    const float* __restrict__ ms, float* __restrict__ out) {
    const int tid = threadIdx.x;
    const int col = tid & 31;   // float4 column: channels 4*col .. 4*col+3
    const int rg  = tid >> 5;   // row group 0..31

    const int gA = blockIdx.x;
    const int gB = blockIdx.x + NBLK;

    const int sA = starts[gA], eA = starts[gA + 1];
    const int sB = starts[gB], eB = starts[gB + 1];

    const f32x4* __restrict__ x4 = (const f32x4*)x;
    f32x4* __restrict__ o4 = (f32x4*)out;

    __shared__ f32x4 s_sum[32][32];   // [rg][col] 16KB
    __shared__ f32x4 s_sq[32][32];    // 16KB
    __shared__ float s_a[C_CH];
    __shared__ float s_d[C_CH];

    // ---------------- phase 1A: read + accumulate graph A ----------------
    {
        f32x4 sum = {0.f, 0.f, 0.f, 0.f};
        f32x4 sq  = {0.f, 0.f, 0.f, 0.f};
        for (int r = sA + rg; r < eA; r += 32) {
            f32x4 v = x4[(size_t)r * (C_CH / 4) + col];
            sum += v;
            sq  += v * v;
        }
        s_sum[rg][col] = sum;
        s_sq[rg][col]  = sq;
    }
    #pragma unroll
    for (int st = 16; st >= 1; st >>= 1) {
        __syncthreads();
        if (rg < st) {
            s_sum[rg][col] += s_sum[rg + st][col];
            s_sq[rg][col]  += s_sq[rg + st][col];
        }
    }
    __syncthreads();
    if (tid < C_CH) {
        const int c  = tid;
        const float fsum = s_sum[0][c >> 2][c & 3];
        const float fsq  = s_sq[0][c >> 2][c & 3];
        const float inv  = 1.0f / (float)max(eA - sA, 1);
        const float m    = fsum * inv;
        const float msc  = ms[c];
        const float var  = fsq * inv - m * m * msc * (2.0f - msc);
        const float a    = w[c] * rsqrtf(var + EPSV);
        s_a[c] = a;
        s_d[c] = bias[c] - a * m * msc;
    }
    __syncthreads();
    const f32x4 aA = ((const f32x4*)s_a)[col];
    const f32x4 dA = ((const f32x4*)s_d)[col];
    __syncthreads();   // everyone has aA/dA before s_* reuse for B

    // ------------- interleaved: write A (IC re-read) || read B -------------
    f32x4 sumB = {0.f, 0.f, 0.f, 0.f};
    f32x4 sqB  = {0.f, 0.f, 0.f, 0.f};
    {
        int rA = sA + rg;
        int rB = sB + rg;
        while (rA < eA || rB < eB) {
            if (rA < eA) {
                const size_t g = (size_t)rA * (C_CH / 4) + col;
                f32x4 v = __builtin_nontemporal_load(&x4[g]);  // IC hit
                __builtin_nontemporal_store(ffma4(aA, v, dA), &o4[g]);
                rA += 32;
            }
            if (rB < eB) {
                f32x4 v = x4[(size_t)rB * (C_CH / 4) + col];   // HBM, allocate IC
                sumB += v;
                sqB  += v * v;
                rB += 32;
            }
        }
    }
    s_sum[rg][col] = sumB;
    s_sq[rg][col]  = sqB;
    #pragma unroll
    for (int st = 16; st >= 1; st >>= 1) {
        __syncthreads();
        if (rg < st) {
            s_sum[rg][col] += s_sum[rg + st][col];
            s_sq[rg][col]  += s_sq[rg + st][col];
        }
    }
    __syncthreads();
    if (tid < C_CH) {
        const int c  = tid;
        const float fsum = s_sum[0][c >> 2][c & 3];
        const float fsq  = s_sq[0][c >> 2][c & 3];
        const float inv  = 1.0f / (float)max(eB - sB, 1);
        const float m    = fsum * inv;
        const float msc  = ms[c];
        const float var  = fsq * inv - m * m * msc * (2.0f - msc);
        const float a    = w[c] * rsqrtf(var + EPSV);
        s_a[c] = a;
        s_d[c] = bias[c] - a * m * msc;
    }
    __syncthreads();
    const f32x4 aB = ((const f32x4*)s_a)[col];
    const f32x4 dB = ((const f32x4*)s_d)[col];

    // ---------------- phase 2B: write graph B (IC re-read) ----------------
    for (int r = sB + rg; r < eB; r += 32) {
        const size_t g = (size_t)r * (C_CH / 4) + col;
        f32x4 v = __builtin_nontemporal_load(&x4[g]);          // IC hit
        __builtin_nontemporal_store(ffma4(aB, v, dB), &o4[g]);
    }
}

extern "C" void kernel_launch(void* const* d_in, const int* in_sizes, int n_in,
                              void* d_out, int out_size, void* d_ws, size_t ws_size,
                              hipStream_t stream) {
    const float* x     = (const float*)d_in[0];
    const int*   batch = (const int*)d_in[1];
    const float* w     = (const float*)d_in[2];
    const float* bias  = (const float*)d_in[3];
    const float* ms    = (const float*)d_in[4];
    const int B = B_GR;                 // reference constant (device scalar d_in[5])
    const int N = in_sizes[1];          // rows

    int* starts = (int*)d_ws;           // [B+1] ints
    float* out = (float*)d_out;

    gn_bounds<<<(B + 1 + 255) / 256, 256, 0, stream>>>(batch, N, B, starts);
    gn_fused2<<<NBLK, 1024, 0, stream>>>(x, starts, w, bias, ms, out);
}